// Round 4
// baseline (427.218 us; speedup 1.0000x reference)
//
#include <hip/hip_runtime.h>
#include <hip/hip_bf16.h>
#include <stdint.h>

typedef __bf16 bf16x8 __attribute__((ext_vector_type(8)));
typedef float f32x4 __attribute__((ext_vector_type(4)));
typedef float f32x16 __attribute__((ext_vector_type(16)));

#define NB_H 16
#define NB_KV 4
#define NB_HD 128
#define NB_B 2
#define NB_S 2048
#define NB_D 2048
#define NB_M (NB_B*NB_S)   /* 4096 */
#define NB_NQKV 3072
#define CAPF 50.0f
#define SCALEF 0.08838834764831845f

__device__ __forceinline__ ushort f2bf(float x){
  uint32_t u = __float_as_uint(x);
  u += 0x7fffu + ((u >> 16) & 1u);
  return (ushort)(u >> 16);
}
__device__ __forceinline__ float bf2f(ushort u){
  return __uint_as_float(((uint32_t)u) << 16);
}
__device__ __forceinline__ void gload_lds16(const void* g, void* l){
  __builtin_amdgcn_global_load_lds(
      (const __attribute__((address_space(1))) uint32_t*)g,
      (__attribute__((address_space(3))) uint32_t*)l, 16, 0, 0);
}

// ---------------- fused fp32 -> bf16 conversion (all 5 tensors, 1 launch) ----------------
__global__ __launch_bounds__(256) void cvt_all(const float* __restrict__ hs,
                                               const float* __restrict__ wq,
                                               const float* __restrict__ wk,
                                               const float* __restrict__ wv,
                                               const float* __restrict__ wo,
                                               ushort* __restrict__ hsb,
                                               ushort* __restrict__ wqkv,
                                               ushort* __restrict__ wob){
  int q = blockIdx.x * blockDim.x + threadIdx.x;   // grid sized exactly
  const float* src; ushort* dst; int i;
  if (q < 2097152)      { src = hs; dst = hsb;            i = q; }
  else if (q < 3145728) { src = wq; dst = wqkv;           i = q - 2097152; }
  else if (q < 3407872) { src = wk; dst = wqkv + 4194304; i = q - 3145728; }
  else if (q < 3670016) { src = wv; dst = wqkv + 5242880; i = q - 3407872; }
  else                  { src = wo; dst = wob;            i = q - 3670016; }
  float4 v = ((const float4*)src)[i];
  ushort4 o;
  o.x = f2bf(v.x); o.y = f2bf(v.y); o.z = f2bf(v.z); o.w = f2bf(v.w);
  ((ushort4*)dst)[i] = o;
}

// ---------------- bf16 GEMM: C[M][N] = A[M][K] * B[N][K]^T (1D grid + XCD swizzle) ----------------
__global__ __launch_bounds__(256) void gemm_bt(const ushort* __restrict__ A,
                                               const ushort* __restrict__ Bw,
                                               ushort* __restrict__ Cb,
                                               float* __restrict__ Cf,
                                               int M, int N, int K, int nbx){
  int nwg = gridDim.x;
  int cpx = nwg >> 3;
  int wg = blockIdx.x;
  int swz = (wg & 7) * cpx + (wg >> 3);
  int bx = swz % nbx, by = swz / nbx;

  __shared__ ushort As[128 * 32];
  __shared__ ushort Bs[128 * 32];
  int tid = threadIdx.x;
  int w = tid >> 6, l = tid & 63;
  int lr = l & 15, lk = l >> 4;
  int row0 = by * 128, col0 = bx * 128;
  int wm = w >> 1, wn = w & 1;

  f32x4 acc[4][4];
#pragma unroll
  for (int mi = 0; mi < 4; ++mi)
#pragma unroll
    for (int nj = 0; nj < 4; ++nj)
      acc[mi][nj] = f32x4{0.f, 0.f, 0.f, 0.f};

  for (int k0 = 0; k0 < K; k0 += 32) {
#pragma unroll
    for (int c = 0; c < 2; ++c) {
      int off = w * 2048 + c * 1024 + l * 16;
      int r = off >> 6;
      int cb = off & 63;
      gload_lds16(A + (size_t)(row0 + r) * K + k0 + (cb >> 1), (char*)As + off);
      gload_lds16(Bw + (size_t)(col0 + r) * K + k0 + (cb >> 1), (char*)Bs + off);
    }
    __syncthreads();
    bf16x8 af[4], bfr[4];
#pragma unroll
    for (int mi = 0; mi < 4; ++mi)
      af[mi] = *(const bf16x8*)(As + (wm * 64 + mi * 16 + lr) * 32 + lk * 8);
#pragma unroll
    for (int nj = 0; nj < 4; ++nj)
      bfr[nj] = *(const bf16x8*)(Bs + (wn * 64 + nj * 16 + lr) * 32 + lk * 8);
    __builtin_amdgcn_s_setprio(1);
#pragma unroll
    for (int mi = 0; mi < 4; ++mi)
#pragma unroll
      for (int nj = 0; nj < 4; ++nj)
        acc[mi][nj] = __builtin_amdgcn_mfma_f32_16x16x32_bf16(af[mi], bfr[nj], acc[mi][nj], 0, 0, 0);
    __builtin_amdgcn_s_setprio(0);
    __syncthreads();
  }

#pragma unroll
  for (int mi = 0; mi < 4; ++mi)
#pragma unroll
    for (int nj = 0; nj < 4; ++nj)
#pragma unroll
      for (int i = 0; i < 4; ++i) {
        int r = row0 + wm * 64 + mi * 16 + lk * 4 + i;
        int c = col0 + wn * 64 + nj * 16 + lr;
        float v = acc[mi][nj][i];
        if (Cb) Cb[(size_t)r * N + c] = f2bf(v);
        else    Cf[(size_t)r * N + c] = v;
      }
}

// ---------------- RoPE in-place on Q (heads 0..15) and K (heads 16..19) ----------------
__global__ __launch_bounds__(256) void rope_kernel(ushort* __restrict__ qkv,
                                                   const float* __restrict__ cosb,
                                                   const float* __restrict__ sinb){
  int idx = blockIdx.x * blockDim.x + threadIdx.x;
  if (idx >= NB_M * 20 * 64) return;
  int row = idx / 1280;
  int rem = idx - row * 1280;
  int head = rem >> 6;
  int d = rem & 63;
  size_t base = (size_t)row * NB_NQKV + head * 128 + d;
  float a = bf2f(qkv[base]);
  float b = bf2f(qkv[base + 64]);
  float c = cosb[row * 128 + d];
  float s = sinb[row * 128 + d];
  qkv[base]      = f2bf(a * c - b * s);
  qkv[base + 64] = f2bf(b * c + a * s);
}

// ---------------- V transpose: vt[b][kv][d][s] ----------------
__global__ __launch_bounds__(256) void vtrans_kernel(const ushort* __restrict__ qkv,
                                                     ushort* __restrict__ vt){
  __shared__ ushort tile[64 * 136];
  int bid = blockIdx.x;
  int s0 = (bid & 31) * 64;
  int kvh = (bid >> 5) & 3;
  int b = bid >> 7;
  int tid = threadIdx.x;
#pragma unroll
  for (int i = 0; i < 4; ++i) {
    int g = tid + i * 256;
    int r = g >> 4, c = g & 15;
    *(uint4*)(tile + r * 136 + c * 8) =
        *(const uint4*)(qkv + (size_t)(b * NB_S + s0 + r) * NB_NQKV + 2560 + kvh * 128 + c * 8);
  }
  __syncthreads();
#pragma unroll
  for (int i = 0; i < 4; ++i) {
    int g = tid + i * 256;
    int dd = g >> 3, c = g & 7;
    union { ushort u[8]; uint4 v; } tmp;
#pragma unroll
    for (int j = 0; j < 8; ++j) tmp.u[j] = tile[(c * 8 + j) * 136 + dd];
    *(uint4*)(vt + ((size_t)(b * NB_KV + kvh) * NB_HD + dd) * NB_S + s0 + c * 8) = tmp.v;
  }
}

// ---------------- flash attention v4: L2-direct K/V, barrier-free main loop ----------------
// grid: 2048 blocks x 128 threads (2 waves). Block = one 32-row q-tile; the two waves
// split the k-tiles (interleaved) and merge at the end (exact: no-max softmax).
// decode: g = blk&7 -> (b,kvh) [XCD affinity: K/V (2MB) stays L2-resident];
//         inner = blk>>3: h_lo = inner&3, qtile = 63 - (inner>>2) [heaviest first].
__global__ __launch_bounds__(128, 4) void attn_kernel(const ushort* __restrict__ qkv,
                                                      const ushort* __restrict__ vt,
                                                      ushort* __restrict__ obuf){
  __shared__ float accbuf[4096];     // wave1's O^T partial: [dt][r][lane]
  __shared__ float lbuf[64];
  __shared__ ushort trbuf[32 * 140]; // epilogue transpose, pad 140 (2-way max)
  const int tid = threadIdx.x;
  const int w = tid >> 6, l = tid & 63;
  const int ql = l & 31, hi = l >> 5;
  const int blk = blockIdx.x;
  const int g = blk & 7;
  const int inner = blk >> 3;
  const int h_lo = inner & 3;
  const int qtile = 63 - (inner >> 2);
  const int b = g >> 2, kvh = g & 3;
  const int h = kvh * 4 + h_lo;
  const int q0 = qtile * 32;
  const int q = q0 + ql;
  const int nkt = (q0 + 95) >> 6;    // tiles with s0 <= q0+31

  const ushort* Kg = qkv + (size_t)b * NB_S * NB_NQKV + 2048 + kvh * 128;
  const ushort* Vg = vt + (size_t)(b * NB_KV + kvh) * NB_HD * NB_S;

  // Q fragments (B-operand: lane holds q-col = ql, d = 16*dc + 8*hi + j)
  bf16x8 qf[8];
  {
    const ushort* qrow = qkv + (size_t)(b * NB_S + q) * NB_NQKV + h * 128 + hi * 8;
#pragma unroll
    for (int dc = 0; dc < 8; ++dc)
      qf[dc] = *(const bf16x8*)(qrow + dc * 16);
  }

  f32x16 acc[4];   // O^T accumulator: acc[dt] = 32d x 32q tile, col q = ql
#pragma unroll
  for (int dt = 0; dt < 4; ++dt)
#pragma unroll
    for (int r = 0; r < 16; ++r) acc[dt][r] = 0.f;
  float l_run = 0.f;

  const float K1 = SCALEF / CAPF;                  // s -> x
  const float KW = SCALEF * 1.4426950408889634f;   // s -> w (= cap*log2e*x)

  for (int kt = w; kt < nkt; kt += 2) {
    const int s0 = kt * 64;
    // S^T = mfma(K, Q): K fragments straight from L2 (per-lane 16B, rows stride 6KB)
    f32x16 st[2];
#pragma unroll
    for (int t = 0; t < 2; ++t) {
#pragma unroll
      for (int r = 0; r < 16; ++r) st[t][r] = 0.f;
      const ushort* krow = Kg + (size_t)(s0 + t * 32 + ql) * NB_NQKV + hi * 8;
#pragma unroll
      for (int dc = 0; dc < 8; ++dc) {
        bf16x8 kf = *(const bf16x8*)(krow + dc * 16);
        st[t] = __builtin_amdgcn_mfma_f32_32x32x16_bf16(kf, qf[dc], st[t], 0, 0, 0);
      }
    }
    // fused poly-tanh soft-cap + exp2 softmax (no max subtraction: capped <= 50)
    const bool full = (s0 + 63 <= q0);             // wave-uniform
    const int qmb = q - s0 - 4 * hi;               // mask: koff <= qmb
    float p[2][16];
    float rs = 0.f;
#pragma unroll
    for (int t = 0; t < 2; ++t)
#pragma unroll
      for (int r = 0; r < 16; ++r) {
        float s = st[t][r];
        float x = s * K1;
        float x2 = x * x;
        float ww = s * KW;
        float t1 = fmaf(x2, 0.13333334f, -0.33333334f);   // (tanh(x)/x - 1)/x2
        float y = fmaf(ww * x2, t1, ww);                  // cap*tanh(x)*log2e
        y = fminf(y, 72.134752f);                         // overflow guard
        if (!full) {
          const int koff = t * 32 + (r & 3) + 8 * (r >> 2);
          y = (koff <= qmb) ? y : -1e30f;
        }
        float pe = __builtin_amdgcn_exp2f(y);
        p[t][r] = pe;
        rs += pe;
      }
    rs += __shfl_xor(rs, 32);
    l_run += rs;
    // pack P to bf16 and exchange 8 words across half-waves
    union { __bf16 hh16[32]; uint u[16]; } Pk;
#pragma unroll
    for (int t = 0; t < 2; ++t)
#pragma unroll
      for (int r = 0; r < 16; ++r)
        Pk.hh16[t * 16 + r] = (__bf16)p[t][r];
    uint rec[2][2][2];
#pragma unroll
    for (int t = 0; t < 2; ++t)
#pragma unroll
      for (int hh = 0; hh < 2; ++hh)
#pragma unroll
        for (int wb = 0; wb < 2; ++wb) {
          uint send = hi ? Pk.u[t * 8 + 4 * hh + wb] : Pk.u[t * 8 + 4 * hh + 2 + wb];
          rec[t][hh][wb] = __shfl_xor(send, 32);
        }
    // O^T += mfma(V^T, P^T): V^T fragments straight from L2 (rows stride 4KB)
#pragma unroll
    for (int c = 0; c < 4; ++c) {
      const int t = c >> 1, hh = c & 1;
      union { uint u[4]; bf16x8 v; } pf;
      pf.u[0] = hi ? rec[t][hh][0] : Pk.u[t * 8 + 4 * hh + 0];
      pf.u[1] = hi ? rec[t][hh][1] : Pk.u[t * 8 + 4 * hh + 1];
      pf.u[2] = hi ? Pk.u[t * 8 + 4 * hh + 2] : rec[t][hh][0];
      pf.u[3] = hi ? Pk.u[t * 8 + 4 * hh + 3] : rec[t][hh][1];
#pragma unroll
      for (int dt = 0; dt < 4; ++dt) {
        bf16x8 vf = *(const bf16x8*)(Vg + (size_t)(dt * 32 + ql) * NB_S + s0 + (c * 2 + hi) * 8);
        acc[dt] = __builtin_amdgcn_mfma_f32_32x32x16_bf16(vf, pf.v, acc[dt], 0, 0, 0);
      }
    }
  }

  // ---- split-k merge (exact: both partials share the identity scaling) ----
  if (w == 1) {
#pragma unroll
    for (int dt = 0; dt < 4; ++dt)
#pragma unroll
      for (int r = 0; r < 16; ++r)
        accbuf[(dt * 16 + r) * 64 + l] = acc[dt][r];
    lbuf[l] = l_run;
  }
  __syncthreads();
  if (w == 0) {
#pragma unroll
    for (int dt = 0; dt < 4; ++dt)
#pragma unroll
      for (int r = 0; r < 16; ++r)
        acc[dt][r] += accbuf[(dt * 16 + r) * 64 + l];
    l_run += lbuf[l];
    const float inv = __builtin_amdgcn_rcpf(l_run);
#pragma unroll
    for (int dt = 0; dt < 4; ++dt)
#pragma unroll
      for (int gg = 0; gg < 4; ++gg) {
        ushort4 o;
        o.x = f2bf(acc[dt][4 * gg + 0] * inv);
        o.y = f2bf(acc[dt][4 * gg + 1] * inv);
        o.z = f2bf(acc[dt][4 * gg + 2] * inv);
        o.w = f2bf(acc[dt][4 * gg + 3] * inv);
        const int d0 = dt * 32 + gg * 8 + hi * 4;
        *(ushort4*)(trbuf + ql * 140 + d0) = o;
      }
  }
  __syncthreads();
  // both waves store: 128 threads, 16 lanes per q-row, 8 rows per pass
#pragma unroll
  for (int i = 0; i < 4; ++i) {
    const int qr = i * 8 + (tid >> 4);
    const int c = tid & 15;
    uint4 v = *(const uint4*)(trbuf + qr * 140 + c * 8);
    *(uint4*)(obuf + (size_t)(b * NB_S + q0 + qr) * NB_D + h * 128 + c * 8) = v;
  }
}

// ---------------- host launch ----------------
extern "C" void kernel_launch(void* const* d_in, const int* in_sizes, int n_in,
                              void* d_out, int out_size, void* d_ws, size_t ws_size,
                              hipStream_t stream) {
  const float* hs   = (const float*)d_in[0];
  const float* cosb = (const float*)d_in[1];
  const float* sinb = (const float*)d_in[2];
  const float* Wq   = (const float*)d_in[3];
  const float* Wk   = (const float*)d_in[4];
  const float* Wv   = (const float*)d_in[5];
  const float* Wo   = (const float*)d_in[6];
  float* out = (float*)d_out;
  char* ws = (char*)d_ws;

  ushort* hsb  = (ushort*)(ws + 0);
  ushort* wqkv = (ushort*)(ws + 16777216);
  ushort* wob  = (ushort*)(ws + 29360128);
  ushort* qkvb = (ushort*)(ws + 37748736);
  ushort* vtb  = (ushort*)(ws + 62914560);
  ushort* ob   = (ushort*)(ws + 67108864);

  cvt_all<<<18432, 256, 0, stream>>>(hs, Wq, Wk, Wv, Wo, hsb, wqkv, wob);

  gemm_bt<<<768, 256, 0, stream>>>(hsb, wqkv, qkvb, nullptr, NB_M, NB_NQKV, NB_D, 24);
  rope_kernel<<<(NB_M * 20 * 64 + 255) / 256, 256, 0, stream>>>(qkvb, cosb, sinb);
  vtrans_kernel<<<NB_B * NB_KV * (NB_S / 64), 256, 0, stream>>>(qkvb, vtb);

  attn_kernel<<<2048, 128, 0, stream>>>(qkvb, vtb, ob);

  gemm_bt<<<512, 256, 0, stream>>>(ob, wob, nullptr, out, NB_M, NB_D, NB_D, 16);
}